// Round 2
// baseline (41996.185 us; speedup 1.0000x reference)
//
#include <hip/hip_runtime.h>

// DA-RNN persistent kernel, round 2: TB=1024 (16 waves/CU), f16 weights
// converted once per call into d_ws (L2-resident ~2.2MB working set),
// v_dot2_f32_f16 packed dots (fp32 accumulate), shuffle-based softmax.

#define B_   1024
#define T_   128     // T_ENCO
#define NI_  128     // N_INP
#define H_   256     // N_HID
#define H4_  1024    // 4*N_HID
#define TD_  24      // T_DECO
#define DS_  30      // decoder steps
#define BB   4       // batch rows per workgroup
#define TB   1024    // threads per block

typedef _Float16 hf_t;
typedef _Float16 half8  __attribute__((ext_vector_type(8)));
typedef _Float16 half2v __attribute__((ext_vector_type(2)));

__device__ __forceinline__ float sigm(float x) {
    return __builtin_amdgcn_rcpf(1.0f + __expf(-x));
}
__device__ __forceinline__ float tanh_f(float x) {
    float e = __expf(2.0f * x);
    return 1.0f - 2.0f * __builtin_amdgcn_rcpf(e + 1.0f);
}
__device__ __forceinline__ float fdot2f(half2v a, half2v b, float c) {
#if __has_builtin(__builtin_amdgcn_fdot2)
    return __builtin_amdgcn_fdot2(a, b, c, false);
#else
    return fmaf((float)a.x, (float)b.x, fmaf((float)a.y, (float)b.y, c));
#endif
}
__device__ __forceinline__ float dot8h(half8 w, half8 x, float acc) {
    acc = fdot2f(__builtin_shufflevector(w, w, 0, 1), __builtin_shufflevector(x, x, 0, 1), acc);
    acc = fdot2f(__builtin_shufflevector(w, w, 2, 3), __builtin_shufflevector(x, x, 2, 3), acc);
    acc = fdot2f(__builtin_shufflevector(w, w, 4, 5), __builtin_shufflevector(x, x, 4, 5), acc);
    acc = fdot2f(__builtin_shufflevector(w, w, 6, 7), __builtin_shufflevector(x, x, 6, 7), acc);
    return acc;
}

// ---- weight f16 layout inside d_ws (offsets in halves) ----
#define W_WE    0u
#define W_UE2   131072u
#define W_EWIH  163840u
#define W_EWHH  294912u
#define W_MWIH  557056u
#define W_MWHH  819200u
#define W_DWIH  1081344u
#define W_DWHH  1343488u
#define W_UDW   1605632u
#define W_WDW   1671168u
#define SCR_A   2097152u             // uex during encoder, udm during decoder (B*128*256)
#define SCR_B   35651584u            // midb (B*128*256)

__global__ void convw_kernel(const float* __restrict__ s0, const float* __restrict__ s1,
                             const float* __restrict__ s2, const float* __restrict__ s3,
                             const float* __restrict__ s4, const float* __restrict__ s5,
                             const float* __restrict__ s6, const float* __restrict__ s7,
                             const float* __restrict__ s8, const float* __restrict__ s9,
                             hf_t* __restrict__ dst) {
    const int gtid = blockIdx.x * blockDim.x + threadIdx.x;
    const int gs   = gridDim.x * blockDim.x;
    for (int i = gtid; i < 131072; i += gs) dst[W_WE   + i] = (hf_t)s0[i];
    for (int i = gtid; i <  32768; i += gs) dst[W_UE2  + i] = (hf_t)s1[i];
    for (int i = gtid; i < 131072; i += gs) dst[W_EWIH + i] = (hf_t)s2[i];
    for (int i = gtid; i < 262144; i += gs) dst[W_EWHH + i] = (hf_t)s3[i];
    for (int i = gtid; i < 262144; i += gs) dst[W_MWIH + i] = (hf_t)s4[i];
    for (int i = gtid; i < 262144; i += gs) dst[W_MWHH + i] = (hf_t)s5[i];
    for (int i = gtid; i < 262144; i += gs) dst[W_DWIH + i] = (hf_t)s6[i];
    for (int i = gtid; i < 262144; i += gs) dst[W_DWHH + i] = (hf_t)s7[i];
    for (int i = gtid; i <  65536; i += gs) dst[W_UDW  + i] = (hf_t)s8[i];
    for (int i = gtid; i < 131072; i += gs) dst[W_WDW  + i] = (hf_t)s9[i];
}

// ---- LDS offsets (floats) ----
#define O_HC    0        // hf [4][512]  [h;c] enc/dec
#define O_CF    1024     // f32 [4][256] c enc/dec
#define O_HM    2048     // hf [4][256]  h mid
#define O_CMF   2560     // f32 [4][256] c mid
#define O_XG    3584     // hf [4][128]  gated x
#define O_XRAW  3840     // f32 [4][128]
#define O_XH    4352     // hf [4][128]  raw x f16
#define O_HCXI  4608     // f32 [4][256]
#define O_SPART 5632     // f32 [1024]
#define O_SBUF  6656     // f32 [4][128]
#define O_GBUF  7168     // f32 [4][1024]
#define O_DINH  11264    // hf [4][256]
#define O_HF    11520    // f32 [4][256] dec h fp32
#define O_VES   12544    // f32 [256]
#define O_VDS   12800    // f32 [256]

__global__ __launch_bounds__(TB, 4) void dsrnn_kernel(
    const float* __restrict__ inp,
    const float* __restrict__ UeW,  const float* __restrict__ Ueb,
    const float* __restrict__ Ue2b,
    const float* __restrict__ Web,
    const float* __restrict__ VeW,  const float* __restrict__ Veb,
    const float* __restrict__ Udb,
    const float* __restrict__ Wdb,
    const float* __restrict__ VdW,  const float* __restrict__ Vdb,
    const float* __restrict__ ebih, const float* __restrict__ ebhh,
    const float* __restrict__ mbih, const float* __restrict__ mbhh,
    const float* __restrict__ dbih, const float* __restrict__ dbhh,
    const float* __restrict__ rW,   const float* __restrict__ rb,
    const hf_t* __restrict__ wb,    // f16 weights base
    hf_t* __restrict__ scrA,        // uex -> udm
    hf_t* __restrict__ scrB,        // midb
    float* __restrict__ out)
{
    __shared__ float sm[16384];
    const int tid = threadIdx.x;
    const int b0  = blockIdx.x * BB;

    hf_t*  hc   = (hf_t*)(sm + O_HC);
    float* cf   = sm + O_CF;
    hf_t*  hm   = (hf_t*)(sm + O_HM);
    float* cmf  = sm + O_CMF;
    hf_t*  xg   = (hf_t*)(sm + O_XG);
    float* xraw = sm + O_XRAW;
    hf_t*  xh   = (hf_t*)(sm + O_XH);
    float* hcxi = sm + O_HCXI;
    float* spart= sm + O_SPART;
    float* sbuf = sm + O_SBUF;
    float* gbuf = sm + O_GBUF;
    hf_t*  dinh = (hf_t*)(sm + O_DINH);
    float* hful = sm + O_HF;
    float* ves  = sm + O_VES;
    float* vds  = sm + O_VDS;

    const hf_t* WeW_h  = wb + W_WE;
    const hf_t* Ue2W_h = wb + W_UE2;
    const hf_t* eWih_h = wb + W_EWIH;
    const hf_t* eWhh_h = wb + W_EWHH;
    const hf_t* mWih_h = wb + W_MWIH;
    const hf_t* mWhh_h = wb + W_MWHH;
    const hf_t* dWih_h = wb + W_DWIH;
    const hf_t* dWhh_h = wb + W_DWHH;
    const hf_t* UdW_h  = wb + W_UDW;
    const hf_t* WdW_h  = wb + W_WDW;

    // ---------- Phase 0: uex[b,j,k] = sum_t X[t,j]*UeW[k,t] + Ueb[k] ----------
    {
        const int k  = tid & 255;
        const int jq = tid >> 8;                  // j quarter (32 j each)
        const float* wrow  = UeW + (size_t)k * T_;
        const float  biask = Ueb[k];
        for (int b = 0; b < BB; ++b) {
            __syncthreads();
            const float* Xg = inp + (size_t)(b0 + b) * T_ * NI_;
            for (int i = tid; i < T_ * NI_; i += TB) sm[i] = Xg[i];
            __syncthreads();
            hf_t* ub = scrA + (size_t)(b0 + b) * NI_ * H_;
            for (int j0 = jq * 32; j0 < jq * 32 + 32; j0 += 4) {
                float a0 = biask, a1 = biask, a2 = biask, a3 = biask;
                for (int t = 0; t < T_; ++t) {
                    float  w  = wrow[t];
                    float4 x4 = *(const float4*)&sm[t * NI_ + j0];
                    a0 = fmaf(w, x4.x, a0); a1 = fmaf(w, x4.y, a1);
                    a2 = fmaf(w, x4.z, a2); a3 = fmaf(w, x4.w, a3);
                }
                ub[(size_t)(j0 + 0) * H_ + k] = (hf_t)a0;
                ub[(size_t)(j0 + 1) * H_ + k] = (hf_t)a1;
                ub[(size_t)(j0 + 2) * H_ + k] = (hf_t)a2;
                ub[(size_t)(j0 + 3) * H_ + k] = (hf_t)a3;
            }
        }
    }
    __syncthreads();
    for (int i = tid; i < 3584; i += TB) sm[i] = 0.0f;   // zero h/c enc+mid
    if (tid < 256) { ves[tid] = VeW[tid]; vds[tid] = VdW[tid]; }
    __syncthreads();

    // ---------- Fused encoder + mid loop ----------
    for (int t = 0; t < T_; ++t) {
        // (a) load x_t
        if (tid < 512) {
            const int b = tid >> 7, j = tid & 127;
            float v = inp[((size_t)(b0 + b) * T_ + t) * NI_ + j];
            xraw[b * NI_ + j] = v;
            xh[b * NI_ + j]   = (hf_t)v;
        }
        __syncthreads();

        // (b) hcxi = We.[h;c] + Web + Ue2.x + Ue2b
        {
            const int k = tid & 255, b = tid >> 8;
            const half8* wr  = (const half8*)(WeW_h  + (size_t)k * (2 * H_));  // 64
            const half8* u2  = (const half8*)(Ue2W_h + (size_t)k * NI_);       // 16
            const half8* hcv = (const half8*)(hc + b * 2 * H_);
            const half8* xv  = (const half8*)(xh + b * NI_);
            float acc = Web[k] + Ue2b[k];
#pragma unroll 8
            for (int i = 0; i < 64; ++i) acc = dot8h(wr[i], hcv[i], acc);
#pragma unroll 8
            for (int i = 0; i < 16; ++i) acc = dot8h(u2[i], xv[i], acc);
            hcxi[b * H_ + k] = acc;
        }
        __syncthreads();

        // (c) half-row scores: spart[(b,j,half)] over 128 k each
        {
            const int b = tid >> 8, jj = tid & 255, j = jj >> 1, hlf = tid & 1;
            const half8* uv = (const half8*)(scrA + ((size_t)(b0 + b) * NI_ + j) * H_ + hlf * 128);
            const float* hx = hcxi + b * H_ + hlf * 128;
            const float* vw = ves + hlf * 128;
            float acc = hlf ? 0.0f : Veb[0];
#pragma unroll 4
            for (int i = 0; i < 16; ++i) {
                half8 u = uv[i];
#pragma unroll
                for (int e = 0; e < 8; ++e) {
                    float tv = tanh_f(hx[i * 8 + e] + (float)u[e]);
                    acc = fmaf(vw[i * 8 + e], tv, acc);
                }
            }
            spart[tid] = acc;
        }
        __syncthreads();

        // (d) softmax per b (one wave per b), gate x
        if (tid < 256) {
            const int b = tid >> 6, lane = tid & 63;
            const int base = b << 8;
            float sA = spart[base + (lane << 1)] + spart[base + (lane << 1) + 1];
            float sB = spart[base + ((lane + 64) << 1)] + spart[base + ((lane + 64) << 1) + 1];
            float m = fmaxf(sA, sB);
            for (int d = 1; d < 64; d <<= 1) m = fmaxf(m, __shfl_xor(m, d));
            float eA = __expf(sA - m), eB = __expf(sB - m);
            float ssum = eA + eB;
            for (int d = 1; d < 64; d <<= 1) ssum += __shfl_xor(ssum, d);
            float inv = 1.0f / ssum;
            xg[b * NI_ + lane]      = (hf_t)(xraw[b * NI_ + lane] * eA * inv);
            xg[b * NI_ + lane + 64] = (hf_t)(xraw[b * NI_ + lane + 64] * eB * inv);
        }
        __syncthreads();

        // (e) encoder gates: (2 outputs) x (2 batch) per thread
        {
            const int o = tid & 511, bh = tid >> 9;
            const int bA = bh * 2, bB2 = bh * 2 + 1;
            const half8* wiA = (const half8*)(eWih_h + (size_t)o * NI_);
            const half8* wiB = (const half8*)(eWih_h + (size_t)(o + 512) * NI_);
            const half8* whA = (const half8*)(eWhh_h + (size_t)o * H_);
            const half8* whB = (const half8*)(eWhh_h + (size_t)(o + 512) * H_);
            const half8* xA = (const half8*)(xg + bA * NI_);
            const half8* xB = (const half8*)(xg + bB2 * NI_);
            const half8* hA = (const half8*)(hc + bA * 2 * H_);   // h part
            const half8* hB = (const half8*)(hc + bB2 * 2 * H_);
            float a00 = ebih[o] + ebhh[o];
            float a10 = ebih[o + 512] + ebhh[o + 512];
            float a01 = a00, a11 = a10;
#pragma unroll 8
            for (int i = 0; i < 16; ++i) {
                half8 w0 = wiA[i], w1 = wiB[i], x0 = xA[i], x1 = xB[i];
                a00 = dot8h(w0, x0, a00); a01 = dot8h(w0, x1, a01);
                a10 = dot8h(w1, x0, a10); a11 = dot8h(w1, x1, a11);
            }
#pragma unroll 8
            for (int i = 0; i < 32; ++i) {
                half8 w0 = whA[i], w1 = whB[i], h0 = hA[i], h1 = hB[i];
                a00 = dot8h(w0, h0, a00); a01 = dot8h(w0, h1, a01);
                a10 = dot8h(w1, h0, a10); a11 = dot8h(w1, h1, a11);
            }
            gbuf[bA * H4_ + o] = a00;        gbuf[bB2 * H4_ + o] = a01;
            gbuf[bA * H4_ + o + 512] = a10;  gbuf[bB2 * H4_ + o + 512] = a11;
        }
        __syncthreads();

        // (f) encoder LSTM update
        {
            const int b = tid >> 8, k = tid & 255;
            float gi = gbuf[b * H4_ + k];
            float gf = gbuf[b * H4_ + H_ + k];
            float gg = gbuf[b * H4_ + 2 * H_ + k];
            float go = gbuf[b * H4_ + 3 * H_ + k];
            float c2 = sigm(gf) * cf[b * H_ + k] + sigm(gi) * tanh_f(gg);
            float h2 = sigm(go) * tanh_f(c2);
            cf[b * H_ + k] = c2;
            hc[b * 2 * H_ + k] = (hf_t)h2;
            hc[b * 2 * H_ + H_ + k] = (hf_t)c2;
        }
        __syncthreads();

        // (g) mid gates
        {
            const int o = tid & 511, bh = tid >> 9;
            const int bA = bh * 2, bB2 = bh * 2 + 1;
            const half8* wiA = (const half8*)(mWih_h + (size_t)o * H_);
            const half8* wiB = (const half8*)(mWih_h + (size_t)(o + 512) * H_);
            const half8* whA = (const half8*)(mWhh_h + (size_t)o * H_);
            const half8* whB = (const half8*)(mWhh_h + (size_t)(o + 512) * H_);
            const half8* eA = (const half8*)(hc + bA * 2 * H_);   // new enc h
            const half8* eB = (const half8*)(hc + bB2 * 2 * H_);
            const half8* mA = (const half8*)(hm + bA * H_);
            const half8* mB = (const half8*)(hm + bB2 * H_);
            float a00 = mbih[o] + mbhh[o];
            float a10 = mbih[o + 512] + mbhh[o + 512];
            float a01 = a00, a11 = a10;
#pragma unroll 8
            for (int i = 0; i < 32; ++i) {
                half8 w0 = wiA[i], w1 = wiB[i], h0 = eA[i], h1 = eB[i];
                a00 = dot8h(w0, h0, a00); a01 = dot8h(w0, h1, a01);
                a10 = dot8h(w1, h0, a10); a11 = dot8h(w1, h1, a11);
            }
#pragma unroll 8
            for (int i = 0; i < 32; ++i) {
                half8 w0 = whA[i], w1 = whB[i], h0 = mA[i], h1 = mB[i];
                a00 = dot8h(w0, h0, a00); a01 = dot8h(w0, h1, a01);
                a10 = dot8h(w1, h0, a10); a11 = dot8h(w1, h1, a11);
            }
            gbuf[bA * H4_ + o] = a00;        gbuf[bB2 * H4_ + o] = a01;
            gbuf[bA * H4_ + o + 512] = a10;  gbuf[bB2 * H4_ + o + 512] = a11;
        }
        __syncthreads();

        // (h) mid LSTM update + store mid (f16)
        {
            const int b = tid >> 8, k = tid & 255;
            float gi = gbuf[b * H4_ + k];
            float gf = gbuf[b * H4_ + H_ + k];
            float gg = gbuf[b * H4_ + 2 * H_ + k];
            float go = gbuf[b * H4_ + 3 * H_ + k];
            float c2 = sigm(gf) * cmf[b * H_ + k] + sigm(gi) * tanh_f(gg);
            float h2 = sigm(go) * tanh_f(c2);
            cmf[b * H_ + k] = c2;
            hm[b * H_ + k] = (hf_t)h2;
            scrB[((size_t)(b0 + b) * T_ + t) * H_ + k] = (hf_t)h2;
        }
        __syncthreads();
    }

    // ---------- udm pass: udm[b,t,o] = Ud.mid + Udb (overwrites uex region) ----------
    {
        const int o = tid & 255, b = tid >> 8;
        const half8* ur = (const half8*)(UdW_h + (size_t)o * H_);
        const float bias = Udb[o];
        for (int t = 0; t < T_; ++t) {
            const half8* mv = (const half8*)(scrB + ((size_t)(b0 + b) * T_ + t) * H_);
            float acc = bias;
#pragma unroll 8
            for (int i = 0; i < 32; ++i) acc = dot8h(ur[i], mv[i], acc);
            scrA[((size_t)(b0 + b) * T_ + t) * H_ + o] = (hf_t)acc;
        }
    }
    __syncthreads();
    for (int i = tid; i < 2048; i += TB) sm[i] = 0.0f;   // zero dec h/c (hc + cf)
    __syncthreads();

    // ---------- Decoder ----------
    for (int s = 0; s < DS_; ++s) {
        // (a') wd = Wd.[h;c] + Wdb
        {
            const int k = tid & 255, b = tid >> 8;
            const half8* wr  = (const half8*)(WdW_h + (size_t)k * (2 * H_));
            const half8* hcv = (const half8*)(hc + b * 2 * H_);
            float acc = Wdb[k];
#pragma unroll 8
            for (int i = 0; i < 64; ++i) acc = dot8h(wr[i], hcv[i], acc);
            hcxi[b * H_ + k] = acc;
        }
        __syncthreads();

        // (b') temporal scores (no softmax)
        {
            const int b = tid >> 8, jj = tid & 255, j = jj >> 1, hlf = tid & 1;
            const half8* uv = (const half8*)(scrA + ((size_t)(b0 + b) * T_ + j) * H_ + hlf * 128);
            const float* hx = hcxi + b * H_ + hlf * 128;
            const float* vw = vds + hlf * 128;
            float acc = hlf ? 0.0f : Vdb[0];
#pragma unroll 4
            for (int i = 0; i < 16; ++i) {
                half8 u = uv[i];
#pragma unroll
                for (int e = 0; e < 8; ++e) {
                    float tv = tanh_f(hx[i * 8 + e] + (float)u[e]);
                    acc = fmaf(vw[i * 8 + e], tv, acc);
                }
            }
            spart[tid] = acc;
        }
        __syncthreads();

        // (c') combine halves
        if (tid < 512) {
            const int b = tid >> 7, j = tid & 127;
            sbuf[b * T_ + j] = spart[(b << 8) + (j << 1)] + spart[(b << 8) + (j << 1) + 1];
        }
        __syncthreads();

        // (d') dec_in[b,h] = sum_j t[b,j] * mid[b,j,h]
        {
            const int b = tid >> 8, h = tid & 255;
            const hf_t* mp = scrB + (size_t)(b0 + b) * T_ * H_ + h;
            float acc = 0.0f;
            for (int j = 0; j < T_; ++j)
                acc = fmaf(sbuf[b * T_ + j], (float)mp[(size_t)j * H_], acc);
            dinh[b * H_ + h] = (hf_t)acc;
        }
        __syncthreads();

        // (e') decoder gates
        {
            const int o = tid & 511, bh = tid >> 9;
            const int bA = bh * 2, bB2 = bh * 2 + 1;
            const half8* wiA = (const half8*)(dWih_h + (size_t)o * H_);
            const half8* wiB = (const half8*)(dWih_h + (size_t)(o + 512) * H_);
            const half8* whA = (const half8*)(dWhh_h + (size_t)o * H_);
            const half8* whB = (const half8*)(dWhh_h + (size_t)(o + 512) * H_);
            const half8* xA = (const half8*)(dinh + bA * H_);
            const half8* xB = (const half8*)(dinh + bB2 * H_);
            const half8* hA = (const half8*)(hc + bA * 2 * H_);
            const half8* hB = (const half8*)(hc + bB2 * 2 * H_);
            float a00 = dbih[o] + dbhh[o];
            float a10 = dbih[o + 512] + dbhh[o + 512];
            float a01 = a00, a11 = a10;
#pragma unroll 8
            for (int i = 0; i < 32; ++i) {
                half8 w0 = wiA[i], w1 = wiB[i], x0 = xA[i], x1 = xB[i];
                a00 = dot8h(w0, x0, a00); a01 = dot8h(w0, x1, a01);
                a10 = dot8h(w1, x0, a10); a11 = dot8h(w1, x1, a11);
            }
#pragma unroll 8
            for (int i = 0; i < 32; ++i) {
                half8 w0 = whA[i], w1 = whB[i], h0 = hA[i], h1 = hB[i];
                a00 = dot8h(w0, h0, a00); a01 = dot8h(w0, h1, a01);
                a10 = dot8h(w1, h0, a10); a11 = dot8h(w1, h1, a11);
            }
            gbuf[bA * H4_ + o] = a00;        gbuf[bB2 * H4_ + o] = a01;
            gbuf[bA * H4_ + o + 512] = a10;  gbuf[bB2 * H4_ + o + 512] = a11;
        }
        __syncthreads();

        // (f') decoder LSTM update
        {
            const int b = tid >> 8, k = tid & 255;
            float gi = gbuf[b * H4_ + k];
            float gf = gbuf[b * H4_ + H_ + k];
            float gg = gbuf[b * H4_ + 2 * H_ + k];
            float go = gbuf[b * H4_ + 3 * H_ + k];
            float c2 = sigm(gf) * cf[b * H_ + k] + sigm(gi) * tanh_f(gg);
            float h2 = sigm(go) * tanh_f(c2);
            cf[b * H_ + k] = c2;
            hc[b * 2 * H_ + k] = (hf_t)h2;
            hc[b * 2 * H_ + H_ + k] = (hf_t)c2;
            hful[b * H_ + k] = h2;
        }
        __syncthreads();

        // (g') out[b, s-6] = rW.h + rb
        if (s >= 6 && tid < 256) {
            const int b = tid >> 6, lane = tid & 63;
            float p = rW[lane] * hful[b * H_ + lane]
                    + rW[lane + 64]  * hful[b * H_ + lane + 64]
                    + rW[lane + 128] * hful[b * H_ + lane + 128]
                    + rW[lane + 192] * hful[b * H_ + lane + 192];
            for (int d = 1; d < 64; d <<= 1) p += __shfl_xor(p, d);
            if (lane == 0) out[(size_t)(b0 + b) * TD_ + (s - 6)] = p + rb[0];
        }
        __syncthreads();
    }
}

extern "C" void kernel_launch(void* const* d_in, const int* in_sizes, int n_in,
                              void* d_out, int out_size, void* d_ws, size_t ws_size,
                              hipStream_t stream) {
    const float* inp  = (const float*)d_in[0];
    const float* UeW  = (const float*)d_in[2];
    const float* Ueb  = (const float*)d_in[3];
    const float* Ue2W = (const float*)d_in[4];
    const float* Ue2b = (const float*)d_in[5];
    const float* WeW  = (const float*)d_in[6];
    const float* Web  = (const float*)d_in[7];
    const float* VeW  = (const float*)d_in[8];
    const float* Veb  = (const float*)d_in[9];
    const float* UdW  = (const float*)d_in[10];
    const float* Udb  = (const float*)d_in[11];
    const float* WdW  = (const float*)d_in[12];
    const float* Wdb  = (const float*)d_in[13];
    const float* VdW  = (const float*)d_in[14];
    const float* Vdb  = (const float*)d_in[15];
    const float* eWih = (const float*)d_in[16];
    const float* eWhh = (const float*)d_in[17];
    const float* ebih = (const float*)d_in[18];
    const float* ebhh = (const float*)d_in[19];
    const float* mWih = (const float*)d_in[20];
    const float* mWhh = (const float*)d_in[21];
    const float* mbih = (const float*)d_in[22];
    const float* mbhh = (const float*)d_in[23];
    const float* dWih = (const float*)d_in[24];
    const float* dWhh = (const float*)d_in[25];
    const float* dbih = (const float*)d_in[26];
    const float* dbhh = (const float*)d_in[27];
    const float* rW   = (const float*)d_in[28];
    const float* rb   = (const float*)d_in[29];

    hf_t* wsb  = (hf_t*)d_ws;
    hf_t* scrA = wsb + SCR_A;
    hf_t* scrB = wsb + SCR_B;

    convw_kernel<<<512, 256, 0, stream>>>(WeW, Ue2W, eWih, eWhh, mWih, mWhh,
                                          dWih, dWhh, UdW, WdW, wsb);

    dsrnn_kernel<<<B_ / BB, TB, 0, stream>>>(
        inp, UeW, Ueb, Ue2b, Web, VeW, Veb, Udb, Wdb, VdW, Vdb,
        ebih, ebhh, mbih, mbhh, dbih, dbhh, rW, rb,
        wsb, scrA, scrB, (float*)d_out);
}

// Round 3
// 10755.688 us; speedup vs baseline: 3.9046x; 3.9046x over previous
//
#include <hip/hip_runtime.h>

// DA-RNN persistent kernel, round 3: weight-deduped interleaved f16 weights
// (L2-resident), transposed uexT/udmT streams with coalesced non-temporal
// loads, k-quarter-split We/Wd GEMV. Zero grid syncs (batch-partitioned).

#define B_   1024
#define T_   128     // T_ENCO
#define NI_  128     // N_INP
#define H_   256     // N_HID
#define H4_  1024    // 4*N_HID
#define TD_  24      // T_DECO
#define DS_  30      // decoder steps
#define BB   4       // batch rows per workgroup
#define TB   1024    // threads per block

typedef _Float16 hf_t;
typedef _Float16 half8  __attribute__((ext_vector_type(8)));
typedef _Float16 half2v __attribute__((ext_vector_type(2)));

__device__ __forceinline__ float sigm(float x) {
    return __builtin_amdgcn_rcpf(1.0f + __expf(-x));
}
__device__ __forceinline__ float tanh_f(float x) {
    float e = __expf(2.0f * x);
    return 1.0f - 2.0f * __builtin_amdgcn_rcpf(e + 1.0f);
}
__device__ __forceinline__ float fdot2f(half2v a, half2v b, float c) {
#if __has_builtin(__builtin_amdgcn_fdot2)
    return __builtin_amdgcn_fdot2(a, b, c, false);
#else
    return fmaf((float)a.x, (float)b.x, fmaf((float)a.y, (float)b.y, c));
#endif
}
__device__ __forceinline__ float dot8h(half8 w, half8 x, float acc) {
    acc = fdot2f(__builtin_shufflevector(w, w, 0, 1), __builtin_shufflevector(x, x, 0, 1), acc);
    acc = fdot2f(__builtin_shufflevector(w, w, 2, 3), __builtin_shufflevector(x, x, 2, 3), acc);
    acc = fdot2f(__builtin_shufflevector(w, w, 4, 5), __builtin_shufflevector(x, x, 4, 5), acc);
    acc = fdot2f(__builtin_shufflevector(w, w, 6, 7), __builtin_shufflevector(x, x, 6, 7), acc);
    return acc;
}
__device__ __forceinline__ hf_t nt_load_h(const hf_t* p) {
#if __has_builtin(__builtin_nontemporal_load)
    return __builtin_nontemporal_load(p);
#else
    return *p;
#endif
}
__device__ __forceinline__ void nt_store_h(hf_t v, hf_t* p) {
#if __has_builtin(__builtin_nontemporal_store)
    __builtin_nontemporal_store(v, p);
#else
    *p = v;
#endif
}

// ---- f16 weight layout inside d_ws (offsets in halves) ----
// Interleaved layouts: gates G'[(i*1024+o)*8+e] = G[o*K + i*8 + e]
//                      WE'/WD'[((kq*16+i)*256+k)*8+e] = W[k*512 + kq*128 + i*8 + e]
//                      UE2'[((kq*4+i)*256+k)*8+e]     = W[k*128 + kq*32  + i*8 + e]
#define W_WE    0u
#define W_UE2   131072u
#define W_EWIH  163840u
#define W_EWHH  294912u
#define W_MWIH  557056u
#define W_MWHH  819200u
#define W_DWIH  1081344u
#define W_DWHH  1343488u
#define W_WD    1605632u
#define W_UD    1736704u
#define SCR_A   2097152u       // uexT [b][k][j] -> udmT [b][o][t]  (33,554,432 halves)
#define SCR_B   35651584u      // midb [b][t][k]                    (33,554,432 halves)

__global__ void convw_kernel(const float* __restrict__ sWE, const float* __restrict__ sUE2,
                             const float* __restrict__ sEI, const float* __restrict__ sEH,
                             const float* __restrict__ sMI, const float* __restrict__ sMH,
                             const float* __restrict__ sDI, const float* __restrict__ sDH,
                             const float* __restrict__ sWD, const float* __restrict__ sUD,
                             hf_t* __restrict__ dst) {
    const int gtid = blockIdx.x * blockDim.x + threadIdx.x;
    const int gs   = gridDim.x * blockDim.x;
    for (int n = gtid; n < 131072; n += gs) {       // WE'
        int e = n & 7, q = n >> 3, k = q & 255, c = q >> 8, kq = c >> 4, i = c & 15;
        dst[W_WE + n] = (hf_t)sWE[k * 512 + kq * 128 + i * 8 + e];
    }
    for (int n = gtid; n < 32768; n += gs) {        // UE2'
        int e = n & 7, q = n >> 3, k = q & 255, c = q >> 8, kq = c >> 2, i = c & 3;
        dst[W_UE2 + n] = (hf_t)sUE2[k * 128 + kq * 32 + i * 8 + e];
    }
    for (int n = gtid; n < 131072; n += gs) {       // EWIH' (K=128)
        int e = n & 7, q = n >> 3, o = q & 1023, i = q >> 10;
        dst[W_EWIH + n] = (hf_t)sEI[o * 128 + i * 8 + e];
    }
    for (int n = gtid; n < 262144; n += gs) {       // K=256 gates
        int e = n & 7, q = n >> 3, o = q & 1023, i = q >> 10;
        int s = o * 256 + i * 8 + e;
        dst[W_EWHH + n] = (hf_t)sEH[s];
        dst[W_MWIH + n] = (hf_t)sMI[s];
        dst[W_MWHH + n] = (hf_t)sMH[s];
        dst[W_DWIH + n] = (hf_t)sDI[s];
        dst[W_DWHH + n] = (hf_t)sDH[s];
    }
    for (int n = gtid; n < 131072; n += gs) {       // WD'
        int e = n & 7, q = n >> 3, k = q & 255, c = q >> 8, kq = c >> 4, i = c & 15;
        dst[W_WD + n] = (hf_t)sWD[k * 512 + kq * 128 + i * 8 + e];
    }
    for (int n = gtid; n < 65536; n += gs)          // UD plain
        dst[W_UD + n] = (hf_t)sUD[n];
}

// ---- LDS offsets (floats) ----
#define O_HC    0        // hf [4][512]  [h;c] enc (later dec)
#define O_CF    1024     // f32 [4][256]
#define O_HM    2048     // hf [4][256]
#define O_CMF   2560     // f32 [4][256]
#define O_XRAW  3584     // f32 [4][128]
#define O_XH    4096     // hf [4][128]
#define O_XG    4352     // hf [4][128]
#define O_HCXI  4608     // f32 [4][256]
#define O_SPART 5632     // f32 [1024]
#define O_SBUF  6656     // f32 [4][128]
#define O_GBUF  7168     // f32 [4096] (partials / gates)
#define O_DINH  11264    // hf [4][256]
#define O_HF    11776    // f32 [4][256]
#define O_VES   12800    // f32 [256]
#define O_VDS   13056    // f32 [256]

__global__ __launch_bounds__(TB, 4) void dsrnn_kernel(
    const float* __restrict__ inp,
    const float* __restrict__ UeW,  const float* __restrict__ Ueb,
    const float* __restrict__ Ue2b,
    const float* __restrict__ Web,
    const float* __restrict__ VeW,  const float* __restrict__ Veb,
    const float* __restrict__ Udb,
    const float* __restrict__ Wdb,
    const float* __restrict__ VdW,  const float* __restrict__ Vdb,
    const float* __restrict__ ebih, const float* __restrict__ ebhh,
    const float* __restrict__ mbih, const float* __restrict__ mbhh,
    const float* __restrict__ dbih, const float* __restrict__ dbhh,
    const float* __restrict__ rW,   const float* __restrict__ rb,
    const hf_t* __restrict__ wb,
    hf_t* __restrict__ scrA,
    hf_t* __restrict__ scrB,
    float* __restrict__ out)
{
    __shared__ float sm[16384];
    const int tid = threadIdx.x;
    const int b0  = blockIdx.x * BB;

    hf_t*  hc   = (hf_t*)(sm + O_HC);
    float* cf   = sm + O_CF;
    hf_t*  hm   = (hf_t*)(sm + O_HM);
    float* cmf  = sm + O_CMF;
    float* xraw = sm + O_XRAW;
    hf_t*  xh   = (hf_t*)(sm + O_XH);
    hf_t*  xg   = (hf_t*)(sm + O_XG);
    float* hcxi = sm + O_HCXI;
    float* spart= sm + O_SPART;
    float* sbuf = sm + O_SBUF;
    float* gbuf = sm + O_GBUF;
    hf_t*  dinh = (hf_t*)(sm + O_DINH);
    float* hful = sm + O_HF;
    float* ves  = sm + O_VES;
    float* vds  = sm + O_VDS;

    // ---------- Phase 0: uexT[b][k][j] = sum_t X[t,j]*UeW[k,t] + Ueb[k] ----------
    {
        const int j = tid & 127, kq8 = tid >> 7;   // kq8: 0..7, 32 k each
        for (int b = 0; b < BB; ++b) {
            __syncthreads();
            const float* Xg = inp + (size_t)(b0 + b) * T_ * NI_;
            for (int i = tid; i < T_ * NI_; i += TB) sm[i] = Xg[i];
            __syncthreads();
            hf_t* ub = scrA + (size_t)(b0 + b) * H_ * NI_;
            for (int k = kq8 * 32; k < kq8 * 32 + 32; ++k) {
                const float* wrow = UeW + (size_t)k * T_;
                float acc = Ueb[k];
#pragma unroll 4
                for (int t = 0; t < T_; ++t) acc = fmaf(wrow[t], sm[t * NI_ + j], acc);
                nt_store_h((hf_t)acc, ub + (size_t)k * NI_ + j);
            }
        }
    }
    __syncthreads();
    for (int i = tid; i < 3584; i += TB) sm[i] = 0.0f;   // zero h/c enc+mid
    if (tid < 256) { ves[tid] = VeW[tid]; vds[tid] = VdW[tid]; }
    __syncthreads();

    // ---------- Fused encoder + mid loop ----------
    for (int t = 0; t < T_; ++t) {
        // (a) load x_t
        if (tid < 512) {
            const int b = tid >> 7, j = tid & 127;
            float v = inp[((size_t)(b0 + b) * T_ + t) * NI_ + j];
            xraw[b * NI_ + j] = v;
            xh[b * NI_ + j]   = (hf_t)v;
        }
        __syncthreads();

        // (b) We.[h;c] + Ue2.x partials, k-quarter split
        {
            const int k = tid & 255, kq = tid >> 8;
            const half8* wWE = (const half8*)(wb + W_WE)  + (size_t)(kq * 16) * 256 + k;
            const half8* wU2 = (const half8*)(wb + W_UE2) + (size_t)(kq * 4)  * 256 + k;
            float a0 = 0.f, a1 = 0.f, a2 = 0.f, a3 = 0.f;
#pragma unroll 8
            for (int i = 0; i < 16; ++i) {
                half8 w = wWE[(size_t)i * 256];
                a0 = dot8h(w, *(const half8*)&hc[0 * 512 + kq * 128 + i * 8], a0);
                a1 = dot8h(w, *(const half8*)&hc[1 * 512 + kq * 128 + i * 8], a1);
                a2 = dot8h(w, *(const half8*)&hc[2 * 512 + kq * 128 + i * 8], a2);
                a3 = dot8h(w, *(const half8*)&hc[3 * 512 + kq * 128 + i * 8], a3);
            }
#pragma unroll
            for (int i = 0; i < 4; ++i) {
                half8 w = wU2[(size_t)i * 256];
                a0 = dot8h(w, *(const half8*)&xh[0 * 128 + kq * 32 + i * 8], a0);
                a1 = dot8h(w, *(const half8*)&xh[1 * 128 + kq * 32 + i * 8], a1);
                a2 = dot8h(w, *(const half8*)&xh[2 * 128 + kq * 32 + i * 8], a2);
                a3 = dot8h(w, *(const half8*)&xh[3 * 128 + kq * 32 + i * 8], a3);
            }
            gbuf[kq * 1024 + 0 * 256 + k] = a0;
            gbuf[kq * 1024 + 1 * 256 + k] = a1;
            gbuf[kq * 1024 + 2 * 256 + k] = a2;
            gbuf[kq * 1024 + 3 * 256 + k] = a3;
        }
        __syncthreads();
        {
            const int b = tid >> 8, k = tid & 255;
            hcxi[b * 256 + k] = gbuf[b * 256 + k] + gbuf[1024 + b * 256 + k]
                              + gbuf[2048 + b * 256 + k] + gbuf[3072 + b * 256 + k]
                              + Web[k] + Ue2b[k];
        }
        __syncthreads();

        // (c) scores from uexT, coalesced nt scalar loads
        {
            const int b = tid >> 8, r = tid & 255, kh = r >> 7, j = r & 127;
            const hf_t* up = scrA + ((size_t)(b0 + b) * 256 + kh * 128) * 128 + j;
            const float* hx = hcxi + b * 256 + kh * 128;
            const float* vw = ves + kh * 128;
            float acc = kh ? 0.f : Veb[0];
#pragma unroll 8
            for (int k2 = 0; k2 < 128; ++k2) {
                float u = (float)nt_load_h(up + (size_t)k2 * 128);
                acc = fmaf(vw[k2], tanh_f(hx[k2] + u), acc);
            }
            spart[tid] = acc;
        }
        __syncthreads();

        // (d) softmax per b (one wave per b), gate x
        if (tid < 256) {
            const int b = tid >> 6, lane = tid & 63;
            const int base = b << 8;
            float sA = spart[base + lane]      + spart[base + 128 + lane];
            float sB = spart[base + 64 + lane] + spart[base + 192 + lane];
            float m = fmaxf(sA, sB);
            for (int d = 1; d < 64; d <<= 1) m = fmaxf(m, __shfl_xor(m, d));
            float eA = __expf(sA - m), eB = __expf(sB - m);
            float ssum = eA + eB;
            for (int d = 1; d < 64; d <<= 1) ssum += __shfl_xor(ssum, d);
            float inv = 1.0f / ssum;
            xg[b * NI_ + lane]      = (hf_t)(xraw[b * NI_ + lane] * eA * inv);
            xg[b * NI_ + lane + 64] = (hf_t)(xraw[b * NI_ + lane + 64] * eB * inv);
        }
        __syncthreads();

        // (e) encoder gates: thread o owns row o (read exactly once)
        {
            const int o = tid;
            const half8* wih = (const half8*)(wb + W_EWIH) + o;
            const half8* whh = (const half8*)(wb + W_EWHH) + o;
            float bias = ebih[o] + ebhh[o];
            float a0 = bias, a1 = bias, a2 = bias, a3 = bias;
#pragma unroll 8
            for (int i = 0; i < 16; ++i) {
                half8 w = wih[(size_t)i * 1024];
                a0 = dot8h(w, *(const half8*)&xg[0 * 128 + i * 8], a0);
                a1 = dot8h(w, *(const half8*)&xg[1 * 128 + i * 8], a1);
                a2 = dot8h(w, *(const half8*)&xg[2 * 128 + i * 8], a2);
                a3 = dot8h(w, *(const half8*)&xg[3 * 128 + i * 8], a3);
            }
#pragma unroll 8
            for (int i = 0; i < 32; ++i) {
                half8 w = whh[(size_t)i * 1024];
                a0 = dot8h(w, *(const half8*)&hc[0 * 512 + i * 8], a0);
                a1 = dot8h(w, *(const half8*)&hc[1 * 512 + i * 8], a1);
                a2 = dot8h(w, *(const half8*)&hc[2 * 512 + i * 8], a2);
                a3 = dot8h(w, *(const half8*)&hc[3 * 512 + i * 8], a3);
            }
            gbuf[0 * 1024 + o] = a0; gbuf[1 * 1024 + o] = a1;
            gbuf[2 * 1024 + o] = a2; gbuf[3 * 1024 + o] = a3;
        }
        __syncthreads();

        // (f) encoder LSTM update
        {
            const int b = tid >> 8, k = tid & 255;
            float gi = gbuf[b * H4_ + k];
            float gf = gbuf[b * H4_ + H_ + k];
            float gg = gbuf[b * H4_ + 2 * H_ + k];
            float go = gbuf[b * H4_ + 3 * H_ + k];
            float c2 = sigm(gf) * cf[b * H_ + k] + sigm(gi) * tanh_f(gg);
            float h2 = sigm(go) * tanh_f(c2);
            cf[b * H_ + k] = c2;
            hc[b * 512 + k]       = (hf_t)h2;
            hc[b * 512 + 256 + k] = (hf_t)c2;
        }
        __syncthreads();

        // (g) mid gates
        {
            const int o = tid;
            const half8* wih = (const half8*)(wb + W_MWIH) + o;
            const half8* whh = (const half8*)(wb + W_MWHH) + o;
            float bias = mbih[o] + mbhh[o];
            float a0 = bias, a1 = bias, a2 = bias, a3 = bias;
#pragma unroll 8
            for (int i = 0; i < 32; ++i) {
                half8 w = wih[(size_t)i * 1024];
                a0 = dot8h(w, *(const half8*)&hc[0 * 512 + i * 8], a0);
                a1 = dot8h(w, *(const half8*)&hc[1 * 512 + i * 8], a1);
                a2 = dot8h(w, *(const half8*)&hc[2 * 512 + i * 8], a2);
                a3 = dot8h(w, *(const half8*)&hc[3 * 512 + i * 8], a3);
            }
#pragma unroll 8
            for (int i = 0; i < 32; ++i) {
                half8 w = whh[(size_t)i * 1024];
                a0 = dot8h(w, *(const half8*)&hm[0 * 256 + i * 8], a0);
                a1 = dot8h(w, *(const half8*)&hm[1 * 256 + i * 8], a1);
                a2 = dot8h(w, *(const half8*)&hm[2 * 256 + i * 8], a2);
                a3 = dot8h(w, *(const half8*)&hm[3 * 256 + i * 8], a3);
            }
            gbuf[0 * 1024 + o] = a0; gbuf[1 * 1024 + o] = a1;
            gbuf[2 * 1024 + o] = a2; gbuf[3 * 1024 + o] = a3;
        }
        __syncthreads();

        // (h) mid LSTM update + store mid
        {
            const int b = tid >> 8, k = tid & 255;
            float gi = gbuf[b * H4_ + k];
            float gf = gbuf[b * H4_ + H_ + k];
            float gg = gbuf[b * H4_ + 2 * H_ + k];
            float go = gbuf[b * H4_ + 3 * H_ + k];
            float c2 = sigm(gf) * cmf[b * H_ + k] + sigm(gi) * tanh_f(gg);
            float h2 = sigm(go) * tanh_f(c2);
            cmf[b * H_ + k] = c2;
            hm[b * 256 + k] = (hf_t)h2;
            scrB[((size_t)(b0 + b) * T_ + t) * H_ + k] = (hf_t)h2;
        }
        __syncthreads();
    }

    // ---------- udm pass: udmT[b][o][t] = UdW[o,:].mid[b,t,:] + Udb[o] ----------
    {
        const int b = tid >> 8, r = tid & 255, oh = r >> 7, tt = r & 127;
        const half8* mrow = (const half8*)(scrB + ((size_t)(b0 + b) * T_ + tt) * H_);
        half8 m[32];
#pragma unroll
        for (int i = 0; i < 32; ++i) m[i] = mrow[i];
        const half8* udw = (const half8*)(wb + W_UD);
        for (int o2 = 0; o2 < 128; ++o2) {
            const int o = oh * 128 + o2;
            const half8* ur = udw + (size_t)o * 32;
            float acc = Udb[o];
#pragma unroll 8
            for (int i = 0; i < 32; ++i) acc = dot8h(ur[i], m[i], acc);
            nt_store_h((hf_t)acc, scrA + ((size_t)(b0 + b) * 256 + o) * 128 + tt);
        }
    }
    __syncthreads();
    for (int i = tid; i < 2048; i += TB) sm[i] = 0.0f;   // zero dec h/c
    __syncthreads();

    // ---------- Decoder ----------
    for (int s = 0; s < DS_; ++s) {
        // (a') Wd.[h;c] partials, k-quarter split
        {
            const int k = tid & 255, kq = tid >> 8;
            const half8* wWD = (const half8*)(wb + W_WD) + (size_t)(kq * 16) * 256 + k;
            float a0 = 0.f, a1 = 0.f, a2 = 0.f, a3 = 0.f;
#pragma unroll 8
            for (int i = 0; i < 16; ++i) {
                half8 w = wWD[(size_t)i * 256];
                a0 = dot8h(w, *(const half8*)&hc[0 * 512 + kq * 128 + i * 8], a0);
                a1 = dot8h(w, *(const half8*)&hc[1 * 512 + kq * 128 + i * 8], a1);
                a2 = dot8h(w, *(const half8*)&hc[2 * 512 + kq * 128 + i * 8], a2);
                a3 = dot8h(w, *(const half8*)&hc[3 * 512 + kq * 128 + i * 8], a3);
            }
            gbuf[kq * 1024 + 0 * 256 + k] = a0;
            gbuf[kq * 1024 + 1 * 256 + k] = a1;
            gbuf[kq * 1024 + 2 * 256 + k] = a2;
            gbuf[kq * 1024 + 3 * 256 + k] = a3;
        }
        __syncthreads();
        {
            const int b = tid >> 8, k = tid & 255;
            hcxi[b * 256 + k] = gbuf[b * 256 + k] + gbuf[1024 + b * 256 + k]
                              + gbuf[2048 + b * 256 + k] + gbuf[3072 + b * 256 + k]
                              + Wdb[k];
        }
        __syncthreads();

        // (b') temporal scores from udmT (no softmax)
        {
            const int b = tid >> 8, r = tid & 255, kh = r >> 7, j = r & 127;
            const hf_t* up = scrA + ((size_t)(b0 + b) * 256 + kh * 128) * 128 + j;
            const float* hx = hcxi + b * 256 + kh * 128;
            const float* vw = vds + kh * 128;
            float acc = kh ? 0.f : Vdb[0];
#pragma unroll 8
            for (int k2 = 0; k2 < 128; ++k2) {
                float u = (float)nt_load_h(up + (size_t)k2 * 128);
                acc = fmaf(vw[k2], tanh_f(hx[k2] + u), acc);
            }
            spart[tid] = acc;
        }
        __syncthreads();
        if (tid < 512) {
            const int b = tid >> 7, j = tid & 127;
            sbuf[b * T_ + j] = spart[(b << 8) + j] + spart[(b << 8) + 128 + j];
        }
        __syncthreads();

        // (d') dec_in[b,h] = sum_j t[b,j] * mid[b,j,h]
        {
            const int b = tid >> 8, h = tid & 255;
            const hf_t* mp = scrB + (size_t)(b0 + b) * T_ * H_ + h;
            float acc = 0.0f;
            for (int j = 0; j < T_; ++j)
                acc = fmaf(sbuf[b * T_ + j], (float)mp[(size_t)j * H_], acc);
            dinh[b * 256 + h] = (hf_t)acc;
        }
        __syncthreads();

        // (e') decoder gates
        {
            const int o = tid;
            const half8* wih = (const half8*)(wb + W_DWIH) + o;
            const half8* whh = (const half8*)(wb + W_DWHH) + o;
            float bias = dbih[o] + dbhh[o];
            float a0 = bias, a1 = bias, a2 = bias, a3 = bias;
#pragma unroll 8
            for (int i = 0; i < 32; ++i) {
                half8 w = wih[(size_t)i * 1024];
                a0 = dot8h(w, *(const half8*)&dinh[0 * 256 + i * 8], a0);
                a1 = dot8h(w, *(const half8*)&dinh[1 * 256 + i * 8], a1);
                a2 = dot8h(w, *(const half8*)&dinh[2 * 256 + i * 8], a2);
                a3 = dot8h(w, *(const half8*)&dinh[3 * 256 + i * 8], a3);
            }
#pragma unroll 8
            for (int i = 0; i < 32; ++i) {
                half8 w = whh[(size_t)i * 1024];
                a0 = dot8h(w, *(const half8*)&hc[0 * 512 + i * 8], a0);
                a1 = dot8h(w, *(const half8*)&hc[1 * 512 + i * 8], a1);
                a2 = dot8h(w, *(const half8*)&hc[2 * 512 + i * 8], a2);
                a3 = dot8h(w, *(const half8*)&hc[3 * 512 + i * 8], a3);
            }
            gbuf[0 * 1024 + o] = a0; gbuf[1 * 1024 + o] = a1;
            gbuf[2 * 1024 + o] = a2; gbuf[3 * 1024 + o] = a3;
        }
        __syncthreads();

        // (f') decoder LSTM update
        {
            const int b = tid >> 8, k = tid & 255;
            float gi = gbuf[b * H4_ + k];
            float gf = gbuf[b * H4_ + H_ + k];
            float gg = gbuf[b * H4_ + 2 * H_ + k];
            float go = gbuf[b * H4_ + 3 * H_ + k];
            float c2 = sigm(gf) * cf[b * H_ + k] + sigm(gi) * tanh_f(gg);
            float h2 = sigm(go) * tanh_f(c2);
            cf[b * H_ + k] = c2;
            hc[b * 512 + k]       = (hf_t)h2;
            hc[b * 512 + 256 + k] = (hf_t)c2;
            hful[b * H_ + k] = h2;
        }
        __syncthreads();

        // (g') out[b, s-6] = rW.h + rb
        if (s >= 6 && tid < 256) {
            const int b = tid >> 6, lane = tid & 63;
            float p = rW[lane]       * hful[b * H_ + lane]
                    + rW[lane + 64]  * hful[b * H_ + lane + 64]
                    + rW[lane + 128] * hful[b * H_ + lane + 128]
                    + rW[lane + 192] * hful[b * H_ + lane + 192];
            for (int d = 1; d < 64; d <<= 1) p += __shfl_xor(p, d);
            if (lane == 0) out[(size_t)(b0 + b) * TD_ + (s - 6)] = p + rb[0];
        }
        __syncthreads();
    }
}

extern "C" void kernel_launch(void* const* d_in, const int* in_sizes, int n_in,
                              void* d_out, int out_size, void* d_ws, size_t ws_size,
                              hipStream_t stream) {
    const float* inp  = (const float*)d_in[0];
    const float* UeW  = (const float*)d_in[2];
    const float* Ueb  = (const float*)d_in[3];
    const float* Ue2W = (const float*)d_in[4];
    const float* Ue2b = (const float*)d_in[5];
    const float* WeW  = (const float*)d_in[6];
    const float* Web  = (const float*)d_in[7];
    const float* VeW  = (const float*)d_in[8];
    const float* Veb  = (const float*)d_in[9];
    const float* UdW  = (const float*)d_in[10];
    const float* Udb  = (const float*)d_in[11];
    const float* WdW  = (const float*)d_in[12];
    const float* Wdb  = (const float*)d_in[13];
    const float* VdW  = (const float*)d_in[14];
    const float* Vdb  = (const float*)d_in[15];
    const float* eWih = (const float*)d_in[16];
    const float* eWhh = (const float*)d_in[17];
    const float* ebih = (const float*)d_in[18];
    const float* ebhh = (const float*)d_in[19];
    const float* mWih = (const float*)d_in[20];
    const float* mWhh = (const float*)d_in[21];
    const float* mbih = (const float*)d_in[22];
    const float* mbhh = (const float*)d_in[23];
    const float* dWih = (const float*)d_in[24];
    const float* dWhh = (const float*)d_in[25];
    const float* dbih = (const float*)d_in[26];
    const float* dbhh = (const float*)d_in[27];
    const float* rW   = (const float*)d_in[28];
    const float* rb   = (const float*)d_in[29];

    hf_t* wsb  = (hf_t*)d_ws;
    hf_t* scrA = wsb + SCR_A;
    hf_t* scrB = wsb + SCR_B;

    convw_kernel<<<512, 256, 0, stream>>>(WeW, Ue2W, eWih, eWhh, mWih, mWhh,
                                          dWih, dWhh, WdW, UdW, wsb);

    dsrnn_kernel<<<B_ / BB, TB, 0, stream>>>(
        inp, UeW, Ueb, Ue2b, Web, VeW, Veb, Udb, Wdb, VdW, Vdb,
        ebih, ebhh, mbih, mbhh, dbih, dbhh, rW, rb,
        wsb, scrA, scrB, (float*)d_out);
}